// Round 1
// baseline (704.010 us; speedup 1.0000x reference)
//
#include <hip/hip_runtime.h>

#define N_NODES 50000
#define N_EDGES 800000
#define CAP 64

// ---------------- build: bucket edges by dst ----------------
__global__ void k_build(const int* __restrict__ ei, int* __restrict__ cnt,
                        int* __restrict__ bucket) {
    int e = blockIdx.x * blockDim.x + threadIdx.x;
    if (e >= N_EDGES) return;
    int s = ei[e];              // src row
    int d = ei[N_EDGES + e];    // dst row
    int pos = atomicAdd(&cnt[d], 1);
    if (pos < CAP) bucket[d * CAP + pos] = s;
}

// ---------------- t1 = x @ [Wl1 | Wr1]  (128 -> 234) ----------------
__global__ void k_gemm1(const float* __restrict__ x, const float* __restrict__ Wl,
                        const float* __restrict__ Wr, float* __restrict__ t1) {
    int i = blockIdx.x;
    int t = threadIdx.x;
    __shared__ float xs[128];
    if (t < 128) xs[t] = x[i * 128 + t];
    __syncthreads();
    if (t < 234) {
        const float* Wc = (t < 117) ? (Wl + t) : (Wr + (t - 117));
        float acc = 0.f;
#pragma unroll 8
        for (int k = 0; k < 128; ++k) acc = fmaf(xs[k], Wc[k * 117], acc);
        t1[i * 234 + t] = acc;
    }
}

// ------------- h1 = relu(mean_gather(t1[:,0:117]) + t1[:,117:234] + b1) -------------
__global__ void k_agg1(const float* __restrict__ t1, const int* __restrict__ cnt,
                       const int* __restrict__ bucket, const float* __restrict__ b1,
                       float* __restrict__ h1) {
    int i = blockIdx.x;
    int j = threadIdx.x;
    int n = cnt[i]; if (n > CAP) n = CAP;
    __shared__ int sb[CAP];
    if (j < n) sb[j] = bucket[i * CAP + j];
    __syncthreads();
    if (j < 117) {
        float acc = 0.f;
        for (int e = 0; e < n; ++e) acc += t1[sb[e] * 234 + j];
        float deg = (float)cnt[i];
        float v = acc / fmaxf(deg, 1.f) + t1[i * 234 + 117 + j] + b1[j];
        h1[i * 117 + j] = fmaxf(v, 0.f);
    }
}

// ---------------- t2 = h1 @ [Wl2 | Wr2]  (117 -> 84) ----------------
__global__ void k_gemm2(const float* __restrict__ h1, const float* __restrict__ Wl,
                        const float* __restrict__ Wr, float* __restrict__ t2) {
    int i = blockIdx.x;
    int t = threadIdx.x;
    __shared__ float hs[117];
    if (t < 117) hs[t] = h1[i * 117 + t];
    __syncthreads();
    if (t < 84) {
        const float* Wc = (t < 42) ? (Wl + t) : (Wr + (t - 42));
        float acc = 0.f;
#pragma unroll 4
        for (int k = 0; k < 117; ++k) acc = fmaf(hs[k], Wc[k * 42], acc);
        t2[i * 84 + t] = acc;
    }
}

// ------------- h2 = relu(mean_gather(t2[:,0:42]) + t2[:,42:84] + b2) -------------
__global__ void k_agg2(const float* __restrict__ t2, const int* __restrict__ cnt,
                       const int* __restrict__ bucket, const float* __restrict__ b2,
                       float* __restrict__ h2) {
    int i = blockIdx.x;
    int j = threadIdx.x;
    int n = cnt[i]; if (n > CAP) n = CAP;
    __shared__ int sb[CAP];
    if (j < n) sb[j] = bucket[i * CAP + j];
    __syncthreads();
    if (j < 42) {
        float acc = 0.f;
        for (int e = 0; e < n; ++e) acc += t2[sb[e] * 84 + j];
        float deg = (float)cnt[i];
        float v = acc / fmaxf(deg, 1.f) + t2[i * 84 + 42 + j] + b2[j];
        h2[i * 42 + j] = fmaxf(v, 0.f);
    }
}

// ------------- mu/lv heads: m2 = mean_gather(h2); out = m2@Wl + h2@Wr + b -------------
__global__ void k_out(const float* __restrict__ h2, const int* __restrict__ cnt,
                      const int* __restrict__ bucket,
                      const float* __restrict__ Wlm, const float* __restrict__ Wrm,
                      const float* __restrict__ bm,
                      const float* __restrict__ Wlv, const float* __restrict__ Wrv,
                      const float* __restrict__ bv,
                      float* __restrict__ out) {
    int i = blockIdx.x;
    int j = threadIdx.x;
    int n = cnt[i]; if (n > CAP) n = CAP;
    __shared__ int sb[CAP];
    __shared__ float sm[42];
    __shared__ float sh[42];
    if (j < n) sb[j] = bucket[i * CAP + j];
    __syncthreads();
    if (j < 42) {
        float acc = 0.f;
        for (int e = 0; e < n; ++e) acc += h2[sb[e] * 42 + j];
        float deg = (float)cnt[i];
        sm[j] = acc / fmaxf(deg, 1.f);
        sh[j] = h2[i * 42 + j];
    }
    __syncthreads();
    if (j < 48) {
        int o = (j < 24) ? j : (j - 24);
        const float* Wl = (j < 24) ? Wlm : Wlv;
        const float* Wr = (j < 24) ? Wrm : Wrv;
        const float* bb = (j < 24) ? bm : bv;
        float acc = bb[o];
#pragma unroll
        for (int k = 0; k < 42; ++k)
            acc += sm[k] * Wl[k * 24 + o] + sh[k] * Wr[k * 24 + o];
        float* dst = (j < 24) ? (out + (size_t)i * 24)
                              : (out + (size_t)N_NODES * 24 + (size_t)i * 24);
        dst[o] = acc;
    }
}

extern "C" void kernel_launch(void* const* d_in, const int* in_sizes, int n_in,
                              void* d_out, int out_size, void* d_ws, size_t ws_size,
                              hipStream_t stream) {
    const float* x   = (const float*)d_in[0];
    const int*   ei  = (const int*)d_in[1];
    const float* Wl1 = (const float*)d_in[2];
    const float* Wr1 = (const float*)d_in[3];
    const float* b1  = (const float*)d_in[4];
    const float* Wl2 = (const float*)d_in[5];
    const float* Wr2 = (const float*)d_in[6];
    const float* b2  = (const float*)d_in[7];
    const float* Wlm = (const float*)d_in[8];
    const float* Wrm = (const float*)d_in[9];
    const float* bm  = (const float*)d_in[10];
    const float* Wlv = (const float*)d_in[11];
    const float* Wrv = (const float*)d_in[12];
    const float* bv  = (const float*)d_in[13];
    float* out = (float*)d_out;

    // workspace layout (bytes, all 256-aligned):
    //   cnt    @ 0          : 50000*4        = 200,000   (round to 204,800)
    //   bucket @ 204,800    : 50000*64*4     = 12,800,000
    //   t1     @ 13,004,800 : 50000*234*4    = 46,800,000   (t2 aliases here later)
    //   h1     @ 59,804,800 : 50000*117*4    = 23,400,000   (h2 aliases here later)
    // total ~83.2 MB
    char* ws = (char*)d_ws;
    int*   cnt    = (int*)(ws);
    int*   bucket = (int*)(ws + 204800);
    float* t1     = (float*)(ws + 13004800);
    float* h1     = (float*)(ws + 59804800);
    float* t2     = t1;   // t1 dead after k_agg1
    float* h2     = h1;   // h1 dead after k_gemm2

    hipMemsetAsync(cnt, 0, N_NODES * sizeof(int), stream);
    k_build<<<(N_EDGES + 255) / 256, 256, 0, stream>>>(ei, cnt, bucket);
    k_gemm1<<<N_NODES, 256, 0, stream>>>(x, Wl1, Wr1, t1);
    k_agg1<<<N_NODES, 128, 0, stream>>>(t1, cnt, bucket, b1, h1);
    k_gemm2<<<N_NODES, 128, 0, stream>>>(h1, Wl2, Wr2, t2);
    k_agg2<<<N_NODES, 64, 0, stream>>>(t2, cnt, bucket, b2, h2);
    k_out<<<N_NODES, 64, 0, stream>>>(h2, cnt, bucket, Wlm, Wrm, bm, Wlv, Wrv, bv, out);
}

// Round 2
// 390.666 us; speedup vs baseline: 1.8021x; 1.8021x over previous
//
#include <hip/hip_runtime.h>

#define N_NODES 50000
#define N_EDGES 800000
#define CAP 64
#define ROWS 16   // nodes per GEMM block; 50000 = 3125 * 16

// ---------------- build: bucket edges by dst ----------------
__global__ void k_build(const int* __restrict__ ei, int* __restrict__ cnt,
                        int* __restrict__ bucket) {
    int e = blockIdx.x * blockDim.x + threadIdx.x;
    if (e >= N_EDGES) return;
    int s = ei[e];              // src row
    int d = ei[N_EDGES + e];    // dst row
    int pos = atomicAdd(&cnt[d], 1);
    if (pos < CAP) bucket[d * CAP + pos] = s;
}

// ---------------- t1 = x @ [Wl1 | Wr1]  (128 -> 117+117), 16 rows/block ----------------
__global__ __launch_bounds__(256) void k_gemm1(const float* __restrict__ x,
                        const float* __restrict__ Wl, const float* __restrict__ Wr,
                        float* __restrict__ t1l, float* __restrict__ t1r) {
    int base = blockIdx.x * ROWS;
    int t = threadIdx.x;
    // transposed tile: xs[k][r], padded to 20 so &xs[k][0] is 16B-aligned (80B rows)
    __shared__ __align__(16) float xs[128][20];
    // stage: global reads fully contiguous (x rows are dense), LDS writes 8-way worst
    for (int idx = t; idx < ROWS * 128; idx += 256) {
        int r = idx >> 7, c = idx & 127;
        xs[c][r] = x[(size_t)base * 128 + idx];
    }
    __syncthreads();
    if (t < 234) {
        const float* Wc = (t < 117) ? (Wl + t) : (Wr + (t - 117));
        float acc[ROWS];
#pragma unroll
        for (int r = 0; r < ROWS; ++r) acc[r] = 0.f;
#pragma unroll 4
        for (int k = 0; k < 128; ++k) {
            float w = Wc[(size_t)k * 117];
            const float4* xv = (const float4*)&xs[k][0];
            float4 x0 = xv[0], x1 = xv[1], x2 = xv[2], x3 = xv[3];
            acc[0]  = fmaf(x0.x, w, acc[0]);  acc[1]  = fmaf(x0.y, w, acc[1]);
            acc[2]  = fmaf(x0.z, w, acc[2]);  acc[3]  = fmaf(x0.w, w, acc[3]);
            acc[4]  = fmaf(x1.x, w, acc[4]);  acc[5]  = fmaf(x1.y, w, acc[5]);
            acc[6]  = fmaf(x1.z, w, acc[6]);  acc[7]  = fmaf(x1.w, w, acc[7]);
            acc[8]  = fmaf(x2.x, w, acc[8]);  acc[9]  = fmaf(x2.y, w, acc[9]);
            acc[10] = fmaf(x2.z, w, acc[10]); acc[11] = fmaf(x2.w, w, acc[11]);
            acc[12] = fmaf(x3.x, w, acc[12]); acc[13] = fmaf(x3.y, w, acc[13]);
            acc[14] = fmaf(x3.z, w, acc[14]); acc[15] = fmaf(x3.w, w, acc[15]);
        }
        float* dst = (t < 117) ? t1l : t1r;
        int col = (t < 117) ? t : (t - 117);
#pragma unroll
        for (int r = 0; r < ROWS; ++r) dst[(size_t)(base + r) * 117 + col] = acc[r];
    }
}

// ------------- h1 = relu(mean_gather(t1l) + t1r_self + b1) -------------
__global__ void k_agg1(const float* __restrict__ t1l, const float* __restrict__ t1r,
                       const int* __restrict__ cnt, const int* __restrict__ bucket,
                       const float* __restrict__ b1, float* __restrict__ h1) {
    int i = blockIdx.x;
    int j = threadIdx.x;
    int n = cnt[i]; if (n > CAP) n = CAP;
    __shared__ int sb[CAP];
    if (j < n) sb[j] = bucket[i * CAP + j];
    __syncthreads();
    if (j < 117) {
        float a0 = 0.f, a1 = 0.f, a2 = 0.f, a3 = 0.f;
        int e = 0;
        for (; e + 4 <= n; e += 4) {
            a0 += t1l[(size_t)sb[e]     * 117 + j];
            a1 += t1l[(size_t)sb[e + 1] * 117 + j];
            a2 += t1l[(size_t)sb[e + 2] * 117 + j];
            a3 += t1l[(size_t)sb[e + 3] * 117 + j];
        }
        for (; e < n; ++e) a0 += t1l[(size_t)sb[e] * 117 + j];
        float acc = (a0 + a1) + (a2 + a3);
        float deg = fmaxf((float)cnt[i], 1.f);
        float v = acc / deg + t1r[(size_t)i * 117 + j] + b1[j];
        h1[(size_t)i * 117 + j] = fmaxf(v, 0.f);
    }
}

// ---------------- t2 = h1 @ [Wl2 | Wr2]  (117 -> 42+42), 16 rows/block ----------------
__global__ __launch_bounds__(128) void k_gemm2(const float* __restrict__ h1,
                        const float* __restrict__ Wl, const float* __restrict__ Wr,
                        float* __restrict__ t2l, float* __restrict__ t2r) {
    int base = blockIdx.x * ROWS;
    int t = threadIdx.x;
    __shared__ __align__(16) float hs[117][20];
    for (int idx = t; idx < ROWS * 117; idx += 128) {
        int r = idx / 117, c = idx - r * 117;
        hs[c][r] = h1[(size_t)base * 117 + idx];   // contiguous global reads
    }
    __syncthreads();
    if (t < 84) {
        const float* Wc = (t < 42) ? (Wl + t) : (Wr + (t - 42));
        float acc[ROWS];
#pragma unroll
        for (int r = 0; r < ROWS; ++r) acc[r] = 0.f;
#pragma unroll 3
        for (int k = 0; k < 117; ++k) {
            float w = Wc[(size_t)k * 42];
            const float4* hv = (const float4*)&hs[k][0];
            float4 x0 = hv[0], x1 = hv[1], x2 = hv[2], x3 = hv[3];
            acc[0]  = fmaf(x0.x, w, acc[0]);  acc[1]  = fmaf(x0.y, w, acc[1]);
            acc[2]  = fmaf(x0.z, w, acc[2]);  acc[3]  = fmaf(x0.w, w, acc[3]);
            acc[4]  = fmaf(x1.x, w, acc[4]);  acc[5]  = fmaf(x1.y, w, acc[5]);
            acc[6]  = fmaf(x1.z, w, acc[6]);  acc[7]  = fmaf(x1.w, w, acc[7]);
            acc[8]  = fmaf(x2.x, w, acc[8]);  acc[9]  = fmaf(x2.y, w, acc[9]);
            acc[10] = fmaf(x2.z, w, acc[10]); acc[11] = fmaf(x2.w, w, acc[11]);
            acc[12] = fmaf(x3.x, w, acc[12]); acc[13] = fmaf(x3.y, w, acc[13]);
            acc[14] = fmaf(x3.z, w, acc[14]); acc[15] = fmaf(x3.w, w, acc[15]);
        }
        float* dst = (t < 42) ? t2l : t2r;
        int col = (t < 42) ? t : (t - 42);
#pragma unroll
        for (int r = 0; r < ROWS; ++r) dst[(size_t)(base + r) * 42 + col] = acc[r];
    }
}

// ------------- h2 = relu(mean_gather(t2l) + t2r_self + b2) -------------
__global__ void k_agg2(const float* __restrict__ t2l, const float* __restrict__ t2r,
                       const int* __restrict__ cnt, const int* __restrict__ bucket,
                       const float* __restrict__ b2, float* __restrict__ h2) {
    int i = blockIdx.x;
    int j = threadIdx.x;
    int n = cnt[i]; if (n > CAP) n = CAP;
    __shared__ int sb[CAP];
    if (j < n) sb[j] = bucket[i * CAP + j];
    __syncthreads();
    if (j < 42) {
        float a0 = 0.f, a1 = 0.f, a2 = 0.f, a3 = 0.f;
        int e = 0;
        for (; e + 4 <= n; e += 4) {
            a0 += t2l[(size_t)sb[e]     * 42 + j];
            a1 += t2l[(size_t)sb[e + 1] * 42 + j];
            a2 += t2l[(size_t)sb[e + 2] * 42 + j];
            a3 += t2l[(size_t)sb[e + 3] * 42 + j];
        }
        for (; e < n; ++e) a0 += t2l[(size_t)sb[e] * 42 + j];
        float acc = (a0 + a1) + (a2 + a3);
        float deg = fmaxf((float)cnt[i], 1.f);
        float v = acc / deg + t2r[(size_t)i * 42 + j] + b2[j];
        h2[(size_t)i * 42 + j] = fmaxf(v, 0.f);
    }
}

// ------------- mu/lv heads: m2 = mean_gather(h2); out = m2@Wl + h2@Wr + b -------------
__global__ void k_out(const float* __restrict__ h2, const int* __restrict__ cnt,
                      const int* __restrict__ bucket,
                      const float* __restrict__ Wlm, const float* __restrict__ Wrm,
                      const float* __restrict__ bm,
                      const float* __restrict__ Wlv, const float* __restrict__ Wrv,
                      const float* __restrict__ bv,
                      float* __restrict__ out) {
    int i = blockIdx.x;
    int j = threadIdx.x;
    int n = cnt[i]; if (n > CAP) n = CAP;
    __shared__ int sb[CAP];
    __shared__ float sm[42];
    __shared__ float sh[42];
    if (j < n) sb[j] = bucket[i * CAP + j];
    __syncthreads();
    if (j < 42) {
        float a0 = 0.f, a1 = 0.f, a2 = 0.f, a3 = 0.f;
        int e = 0;
        for (; e + 4 <= n; e += 4) {
            a0 += h2[(size_t)sb[e]     * 42 + j];
            a1 += h2[(size_t)sb[e + 1] * 42 + j];
            a2 += h2[(size_t)sb[e + 2] * 42 + j];
            a3 += h2[(size_t)sb[e + 3] * 42 + j];
        }
        for (; e < n; ++e) a0 += h2[(size_t)sb[e] * 42 + j];
        float acc = (a0 + a1) + (a2 + a3);
        float deg = fmaxf((float)cnt[i], 1.f);
        sm[j] = acc / deg;
        sh[j] = h2[(size_t)i * 42 + j];
    }
    __syncthreads();
    if (j < 48) {
        int o = (j < 24) ? j : (j - 24);
        const float* Wl = (j < 24) ? Wlm : Wlv;
        const float* Wr = (j < 24) ? Wrm : Wrv;
        const float* bb = (j < 24) ? bm : bv;
        float acc = bb[o];
#pragma unroll
        for (int k = 0; k < 42; ++k)
            acc += sm[k] * Wl[k * 24 + o] + sh[k] * Wr[k * 24 + o];
        float* dst = (j < 24) ? (out + (size_t)i * 24)
                              : (out + (size_t)N_NODES * 24 + (size_t)i * 24);
        dst[o] = acc;
    }
}

extern "C" void kernel_launch(void* const* d_in, const int* in_sizes, int n_in,
                              void* d_out, int out_size, void* d_ws, size_t ws_size,
                              hipStream_t stream) {
    const float* x   = (const float*)d_in[0];
    const int*   ei  = (const int*)d_in[1];
    const float* Wl1 = (const float*)d_in[2];
    const float* Wr1 = (const float*)d_in[3];
    const float* b1  = (const float*)d_in[4];
    const float* Wl2 = (const float*)d_in[5];
    const float* Wr2 = (const float*)d_in[6];
    const float* b2  = (const float*)d_in[7];
    const float* Wlm = (const float*)d_in[8];
    const float* Wrm = (const float*)d_in[9];
    const float* bm  = (const float*)d_in[10];
    const float* Wlv = (const float*)d_in[11];
    const float* Wrv = (const float*)d_in[12];
    const float* bv  = (const float*)d_in[13];
    float* out = (float*)d_out;

    // workspace layout (bytes):
    //   cnt    @ 0          : 200,000  (pad to 204,800)
    //   bucket @ 204,800    : 12,800,000            -> 13,004,800
    //   t1l    @ 13,004,800 : 23,400,000            -> 36,404,800
    //   t1r    @ 36,404,800 : 23,400,000            -> 59,804,800
    //   h1     @ 59,804,800 : 23,400,000            -> 83,204,800
    //   t2l    @ 13,004,800 (alias t1l, dead after k_agg1) :  8,400,000
    //   t2r    @ 21,404,800 :  8,400,000
    //   h2     @ 29,804,800 :  8,400,000  (h1 still live during k_gemm2 — no overlap)
    char* ws = (char*)d_ws;
    int*   cnt    = (int*)(ws);
    int*   bucket = (int*)(ws + 204800);
    float* t1l    = (float*)(ws + 13004800);
    float* t1r    = (float*)(ws + 36404800);
    float* h1     = (float*)(ws + 59804800);
    float* t2l    = (float*)(ws + 13004800);
    float* t2r    = (float*)(ws + 21404800);
    float* h2     = (float*)(ws + 29804800);

    hipMemsetAsync(cnt, 0, N_NODES * sizeof(int), stream);
    k_build<<<(N_EDGES + 255) / 256, 256, 0, stream>>>(ei, cnt, bucket);
    k_gemm1<<<N_NODES / ROWS, 256, 0, stream>>>(x, Wl1, Wr1, t1l, t1r);
    k_agg1<<<N_NODES, 128, 0, stream>>>(t1l, t1r, cnt, bucket, b1, h1);
    k_gemm2<<<N_NODES / ROWS, 128, 0, stream>>>(h1, Wl2, Wr2, t2l, t2r);
    k_agg2<<<N_NODES, 64, 0, stream>>>(t2l, t2r, cnt, bucket, b2, h2);
    k_out<<<N_NODES, 64, 0, stream>>>(h2, cnt, bucket, Wlm, Wrm, bm, Wlv, Wrv, bv, out);
}

// Round 3
// 362.642 us; speedup vs baseline: 1.9413x; 1.0773x over previous
//
#include <hip/hip_runtime.h>

#define N_NODES 50000
#define N_EDGES 800000
#define CAP 64
#define ROWS 16   // nodes per GEMM block; 50000 = 3125 * 16

typedef _Float16 f16;
typedef unsigned short ushort_t;

// ---------------- build: bucket edges by dst (ushort src ids) ----------------
__global__ void k_build(const int* __restrict__ ei, int* __restrict__ cnt,
                        ushort_t* __restrict__ bucket) {
    int e = blockIdx.x * blockDim.x + threadIdx.x;
    if (e >= N_EDGES) return;
    int s = ei[e];              // src row  (< 50000, fits ushort)
    int d = ei[N_EDGES + e];    // dst row
    int pos = atomicAdd(&cnt[d], 1);
    if (pos < CAP) bucket[d * CAP + pos] = (ushort_t)s;
}

// ------- t1 = x @ [Wl1 | Wr1]  (128 -> 117+117); Wl-part stored fp16, 256B rows -------
__global__ __launch_bounds__(256) void k_gemm1(const float* __restrict__ x,
                        const float* __restrict__ Wl, const float* __restrict__ Wr,
                        f16* __restrict__ t1l, float* __restrict__ t1r) {
    int base = blockIdx.x * ROWS;
    int t = threadIdx.x;
    __shared__ __align__(16) float xs[128][20];   // transposed tile, pad 20 keeps 16B align
    for (int idx = t; idx < ROWS * 128; idx += 256) {
        int r = idx >> 7, c = idx & 127;
        xs[c][r] = x[(size_t)base * 128 + idx];
    }
    __syncthreads();
    if (t < 234) {
        const float* Wc = (t < 117) ? (Wl + t) : (Wr + (t - 117));
        float acc[ROWS];
#pragma unroll
        for (int r = 0; r < ROWS; ++r) acc[r] = 0.f;
#pragma unroll 4
        for (int k = 0; k < 128; ++k) {
            float w = Wc[(size_t)k * 117];
            const float4* xv = (const float4*)&xs[k][0];
            float4 x0 = xv[0], x1 = xv[1], x2 = xv[2], x3 = xv[3];
            acc[0]  = fmaf(x0.x, w, acc[0]);  acc[1]  = fmaf(x0.y, w, acc[1]);
            acc[2]  = fmaf(x0.z, w, acc[2]);  acc[3]  = fmaf(x0.w, w, acc[3]);
            acc[4]  = fmaf(x1.x, w, acc[4]);  acc[5]  = fmaf(x1.y, w, acc[5]);
            acc[6]  = fmaf(x1.z, w, acc[6]);  acc[7]  = fmaf(x1.w, w, acc[7]);
            acc[8]  = fmaf(x2.x, w, acc[8]);  acc[9]  = fmaf(x2.y, w, acc[9]);
            acc[10] = fmaf(x2.z, w, acc[10]); acc[11] = fmaf(x2.w, w, acc[11]);
            acc[12] = fmaf(x3.x, w, acc[12]); acc[13] = fmaf(x3.y, w, acc[13]);
            acc[14] = fmaf(x3.z, w, acc[14]); acc[15] = fmaf(x3.w, w, acc[15]);
        }
        if (t < 117) {
#pragma unroll
            for (int r = 0; r < ROWS; ++r)
                t1l[(size_t)(base + r) * 128 + t] = (f16)acc[r];
        } else {
            int col = t - 117;
#pragma unroll
            for (int r = 0; r < ROWS; ++r)
                t1r[(size_t)(base + r) * 117 + col] = acc[r];
        }
    }
}

// ------------- h1 = relu(mean_gather(t1l) + t1r_self + b1) -------------
__global__ void k_agg1(const f16* __restrict__ t1l, const float* __restrict__ t1r,
                       const int* __restrict__ cnt, const ushort_t* __restrict__ bucket,
                       const float* __restrict__ b1, float* __restrict__ h1) {
    int i = blockIdx.x;
    int j = threadIdx.x;
    int n = cnt[i]; if (n > CAP) n = CAP;
    __shared__ int sb[CAP];
    if (j < n) sb[j] = (int)bucket[i * CAP + j];
    __syncthreads();
    if (j < 117) {
        float a0=0.f,a1=0.f,a2=0.f,a3=0.f,a4=0.f,a5=0.f,a6=0.f,a7=0.f;
        int e = 0;
        for (; e + 8 <= n; e += 8) {
            a0 += (float)t1l[(size_t)sb[e]     * 128 + j];
            a1 += (float)t1l[(size_t)sb[e + 1] * 128 + j];
            a2 += (float)t1l[(size_t)sb[e + 2] * 128 + j];
            a3 += (float)t1l[(size_t)sb[e + 3] * 128 + j];
            a4 += (float)t1l[(size_t)sb[e + 4] * 128 + j];
            a5 += (float)t1l[(size_t)sb[e + 5] * 128 + j];
            a6 += (float)t1l[(size_t)sb[e + 6] * 128 + j];
            a7 += (float)t1l[(size_t)sb[e + 7] * 128 + j];
        }
        for (; e < n; ++e) a0 += (float)t1l[(size_t)sb[e] * 128 + j];
        float acc = ((a0 + a1) + (a2 + a3)) + ((a4 + a5) + (a6 + a7));
        float deg = fmaxf((float)cnt[i], 1.f);
        float v = acc / deg + t1r[(size_t)i * 117 + j] + b1[j];
        h1[(size_t)i * 117 + j] = fmaxf(v, 0.f);
    }
}

// ------- t2 = h1 @ [Wl2 | Wr2]  (117 -> 42+42); Wl-part stored fp16, 128B rows -------
__global__ __launch_bounds__(128) void k_gemm2(const float* __restrict__ h1,
                        const float* __restrict__ Wl, const float* __restrict__ Wr,
                        f16* __restrict__ t2l, float* __restrict__ t2r) {
    int base = blockIdx.x * ROWS;
    int t = threadIdx.x;
    __shared__ __align__(16) float hs[117][20];
    for (int idx = t; idx < ROWS * 117; idx += 128) {
        int r = idx / 117, c = idx - r * 117;
        hs[c][r] = h1[(size_t)base * 117 + idx];
    }
    __syncthreads();
    if (t < 84) {
        const float* Wc = (t < 42) ? (Wl + t) : (Wr + (t - 42));
        float acc[ROWS];
#pragma unroll
        for (int r = 0; r < ROWS; ++r) acc[r] = 0.f;
#pragma unroll 3
        for (int k = 0; k < 117; ++k) {
            float w = Wc[(size_t)k * 42];
            const float4* hv = (const float4*)&hs[k][0];
            float4 x0 = hv[0], x1 = hv[1], x2 = hv[2], x3 = hv[3];
            acc[0]  = fmaf(x0.x, w, acc[0]);  acc[1]  = fmaf(x0.y, w, acc[1]);
            acc[2]  = fmaf(x0.z, w, acc[2]);  acc[3]  = fmaf(x0.w, w, acc[3]);
            acc[4]  = fmaf(x1.x, w, acc[4]);  acc[5]  = fmaf(x1.y, w, acc[5]);
            acc[6]  = fmaf(x1.z, w, acc[6]);  acc[7]  = fmaf(x1.w, w, acc[7]);
            acc[8]  = fmaf(x2.x, w, acc[8]);  acc[9]  = fmaf(x2.y, w, acc[9]);
            acc[10] = fmaf(x2.z, w, acc[10]); acc[11] = fmaf(x2.w, w, acc[11]);
            acc[12] = fmaf(x3.x, w, acc[12]); acc[13] = fmaf(x3.y, w, acc[13]);
            acc[14] = fmaf(x3.z, w, acc[14]); acc[15] = fmaf(x3.w, w, acc[15]);
        }
        if (t < 42) {
#pragma unroll
            for (int r = 0; r < ROWS; ++r)
                t2l[(size_t)(base + r) * 64 + t] = (f16)acc[r];
        } else {
            int col = t - 42;
#pragma unroll
            for (int r = 0; r < ROWS; ++r)
                t2r[(size_t)(base + r) * 42 + col] = acc[r];
        }
    }
}

// ------ h2 = relu(mean_gather(t2l) + t2r_self + b2); write fp32 (self) + fp16 (gather) ------
__global__ void k_agg2(const f16* __restrict__ t2l, const float* __restrict__ t2r,
                       const int* __restrict__ cnt, const ushort_t* __restrict__ bucket,
                       const float* __restrict__ b2,
                       float* __restrict__ h2f, f16* __restrict__ h2h) {
    int i = blockIdx.x;
    int j = threadIdx.x;
    int n = cnt[i]; if (n > CAP) n = CAP;
    __shared__ int sb[CAP];
    if (j < n) sb[j] = (int)bucket[i * CAP + j];
    __syncthreads();
    if (j < 42) {
        float a0=0.f,a1=0.f,a2=0.f,a3=0.f,a4=0.f,a5=0.f,a6=0.f,a7=0.f;
        int e = 0;
        for (; e + 8 <= n; e += 8) {
            a0 += (float)t2l[(size_t)sb[e]     * 64 + j];
            a1 += (float)t2l[(size_t)sb[e + 1] * 64 + j];
            a2 += (float)t2l[(size_t)sb[e + 2] * 64 + j];
            a3 += (float)t2l[(size_t)sb[e + 3] * 64 + j];
            a4 += (float)t2l[(size_t)sb[e + 4] * 64 + j];
            a5 += (float)t2l[(size_t)sb[e + 5] * 64 + j];
            a6 += (float)t2l[(size_t)sb[e + 6] * 64 + j];
            a7 += (float)t2l[(size_t)sb[e + 7] * 64 + j];
        }
        for (; e < n; ++e) a0 += (float)t2l[(size_t)sb[e] * 64 + j];
        float acc = ((a0 + a1) + (a2 + a3)) + ((a4 + a5) + (a6 + a7));
        float deg = fmaxf((float)cnt[i], 1.f);
        float v = acc / deg + t2r[(size_t)i * 42 + j] + b2[j];
        v = fmaxf(v, 0.f);
        h2f[(size_t)i * 42 + j] = v;
        h2h[(size_t)i * 64 + j] = (f16)v;
    }
}

// ------------- mu/lv heads: m2 = mean_gather(h2h); out = m2@Wl + h2f@Wr + b -------------
__global__ void k_out(const float* __restrict__ h2f, const f16* __restrict__ h2h,
                      const int* __restrict__ cnt, const ushort_t* __restrict__ bucket,
                      const float* __restrict__ Wlm, const float* __restrict__ Wrm,
                      const float* __restrict__ bm,
                      const float* __restrict__ Wlv, const float* __restrict__ Wrv,
                      const float* __restrict__ bv,
                      float* __restrict__ out) {
    int i = blockIdx.x;
    int j = threadIdx.x;
    int n = cnt[i]; if (n > CAP) n = CAP;
    __shared__ int sb[CAP];
    __shared__ float sm[42];
    __shared__ float sh[42];
    if (j < n) sb[j] = (int)bucket[i * CAP + j];
    __syncthreads();
    if (j < 42) {
        float a0=0.f,a1=0.f,a2=0.f,a3=0.f,a4=0.f,a5=0.f,a6=0.f,a7=0.f;
        int e = 0;
        for (; e + 8 <= n; e += 8) {
            a0 += (float)h2h[(size_t)sb[e]     * 64 + j];
            a1 += (float)h2h[(size_t)sb[e + 1] * 64 + j];
            a2 += (float)h2h[(size_t)sb[e + 2] * 64 + j];
            a3 += (float)h2h[(size_t)sb[e + 3] * 64 + j];
            a4 += (float)h2h[(size_t)sb[e + 4] * 64 + j];
            a5 += (float)h2h[(size_t)sb[e + 5] * 64 + j];
            a6 += (float)h2h[(size_t)sb[e + 6] * 64 + j];
            a7 += (float)h2h[(size_t)sb[e + 7] * 64 + j];
        }
        for (; e < n; ++e) a0 += (float)h2h[(size_t)sb[e] * 64 + j];
        float acc = ((a0 + a1) + (a2 + a3)) + ((a4 + a5) + (a6 + a7));
        float deg = fmaxf((float)cnt[i], 1.f);
        sm[j] = acc / deg;
        sh[j] = h2f[(size_t)i * 42 + j];
    }
    __syncthreads();
    if (j < 48) {
        int o = (j < 24) ? j : (j - 24);
        const float* Wl = (j < 24) ? Wlm : Wlv;
        const float* Wr = (j < 24) ? Wrm : Wrv;
        const float* bb = (j < 24) ? bm : bv;
        float acc = bb[o];
#pragma unroll
        for (int k = 0; k < 42; ++k)
            acc += sm[k] * Wl[k * 24 + o] + sh[k] * Wr[k * 24 + o];
        float* dst = (j < 24) ? (out + (size_t)i * 24)
                              : (out + (size_t)N_NODES * 24 + (size_t)i * 24);
        dst[o] = acc;
    }
}

extern "C" void kernel_launch(void* const* d_in, const int* in_sizes, int n_in,
                              void* d_out, int out_size, void* d_ws, size_t ws_size,
                              hipStream_t stream) {
    const float* x   = (const float*)d_in[0];
    const int*   ei  = (const int*)d_in[1];
    const float* Wl1 = (const float*)d_in[2];
    const float* Wr1 = (const float*)d_in[3];
    const float* b1  = (const float*)d_in[4];
    const float* Wl2 = (const float*)d_in[5];
    const float* Wr2 = (const float*)d_in[6];
    const float* b2  = (const float*)d_in[7];
    const float* Wlm = (const float*)d_in[8];
    const float* Wrm = (const float*)d_in[9];
    const float* bm  = (const float*)d_in[10];
    const float* Wlv = (const float*)d_in[11];
    const float* Wrv = (const float*)d_in[12];
    const float* bv  = (const float*)d_in[13];
    float* out = (float*)d_out;

    // workspace layout (bytes):
    //   cnt    @ 0          : 200,000  (pad 204,800)
    //   bucket @ 204,800    : 50000*64*2 =  6,400,000 -> 6,604,800
    //   t1l_h  @ 6,604,800  : 50000*128*2 = 12,800,000 -> 19,404,800   [dead after agg1]
    //   t1r    @ 19,404,800 : 50000*117*4 = 23,400,000 -> 42,804,800   [dead after agg1]
    //   h1     @ 42,804,800 : 23,400,000 -> 66,204,800                 [dead after gemm2]
    //   t2l_h  @ 6,604,800  : 50000*64*2 =  6,400,000 (alias t1l_h)
    //   t2r    @ 19,404,800 : 50000*42*4 =  8,400,000 (alias t1r head)
    //   h2f    @ 27,804,800 :  8,400,000 (within old t1r region)
    //   h2h    @ 36,204,800 : 50000*64*2 =  6,400,000 -> 42,604,800 (within old t1r region)
    // total 66.3 MB (< 83.2 MB used in prior passing round)
    char* ws = (char*)d_ws;
    int*      cnt    = (int*)(ws);
    ushort_t* bucket = (ushort_t*)(ws + 204800);
    f16*      t1l    = (f16*)(ws + 6604800);
    float*    t1r    = (float*)(ws + 19404800);
    float*    h1     = (float*)(ws + 42804800);
    f16*      t2l    = (f16*)(ws + 6604800);
    float*    t2r    = (float*)(ws + 19404800);
    float*    h2f    = (float*)(ws + 27804800);
    f16*      h2h    = (f16*)(ws + 36204800);

    hipMemsetAsync(cnt, 0, N_NODES * sizeof(int), stream);
    k_build<<<(N_EDGES + 255) / 256, 256, 0, stream>>>(ei, cnt, bucket);
    k_gemm1<<<N_NODES / ROWS, 256, 0, stream>>>(x, Wl1, Wr1, t1l, t1r);
    k_agg1<<<N_NODES, 128, 0, stream>>>(t1l, t1r, cnt, bucket, b1, h1);
    k_gemm2<<<N_NODES / ROWS, 128, 0, stream>>>(h1, Wl2, Wr2, t2l, t2r);
    k_agg2<<<N_NODES, 64, 0, stream>>>(t2l, t2r, cnt, bucket, b2, h2f, h2h);
    k_out<<<N_NODES, 64, 0, stream>>>(h2f, h2h, cnt, bucket, Wlm, Wrm, bm, Wlv, Wrv, bv, out);
}

// Round 4
// 320.375 us; speedup vs baseline: 2.1975x; 1.1319x over previous
//
#include <hip/hip_runtime.h>

#define N_NODES 50000
#define N_EDGES 800000
#define CAP 64
#define ROWS 16   // nodes per GEMM1 block; 50000 = 3125 * 16

typedef _Float16 f16;
typedef unsigned short u16;
typedef f16 f16x2 __attribute__((ext_vector_type(2)));
typedef f16 f16x4 __attribute__((ext_vector_type(4)));

// ---------------- build: bucket edges by dst (ushort src ids) ----------------
__global__ void k_build(const int* __restrict__ ei, int* __restrict__ cnt,
                        u16* __restrict__ bucket) {
    int e = blockIdx.x * blockDim.x + threadIdx.x;
    if (e >= N_EDGES) return;
    int s = ei[e];
    int d = ei[N_EDGES + e];
    int pos = atomicAdd(&cnt[d], 1);
    if (pos < CAP) bucket[d * CAP + pos] = (u16)s;
}

// ------- t1l = x@Wl1 (f16, stride 128, cols 117..127 zeroed)
// ------- t1r = x@Wr1 + b1 (fp32, stride 120, cols 117..119 zeroed) -------
__global__ __launch_bounds__(256) void k_gemm1(const float* __restrict__ x,
                        const float* __restrict__ Wl, const float* __restrict__ Wr,
                        const float* __restrict__ b1,
                        f16* __restrict__ t1l, float* __restrict__ t1r) {
    int base = blockIdx.x * ROWS;
    int t = threadIdx.x;
    __shared__ __align__(16) float xs[128][20];
    for (int idx = t; idx < ROWS * 128; idx += 256) {
        int r = idx >> 7, c = idx & 127;
        xs[c][r] = x[(size_t)base * 128 + idx];
    }
    __syncthreads();
    if (t < 234) {
        const float* Wc = (t < 117) ? (Wl + t) : (Wr + (t - 117));
        float acc[ROWS];
#pragma unroll
        for (int r = 0; r < ROWS; ++r) acc[r] = 0.f;
#pragma unroll 4
        for (int k = 0; k < 128; ++k) {
            float w = Wc[(size_t)k * 117];
            const float4* xv = (const float4*)&xs[k][0];
            float4 x0 = xv[0], x1 = xv[1], x2 = xv[2], x3 = xv[3];
            acc[0]  = fmaf(x0.x, w, acc[0]);  acc[1]  = fmaf(x0.y, w, acc[1]);
            acc[2]  = fmaf(x0.z, w, acc[2]);  acc[3]  = fmaf(x0.w, w, acc[3]);
            acc[4]  = fmaf(x1.x, w, acc[4]);  acc[5]  = fmaf(x1.y, w, acc[5]);
            acc[6]  = fmaf(x1.z, w, acc[6]);  acc[7]  = fmaf(x1.w, w, acc[7]);
            acc[8]  = fmaf(x2.x, w, acc[8]);  acc[9]  = fmaf(x2.y, w, acc[9]);
            acc[10] = fmaf(x2.z, w, acc[10]); acc[11] = fmaf(x2.w, w, acc[11]);
            acc[12] = fmaf(x3.x, w, acc[12]); acc[13] = fmaf(x3.y, w, acc[13]);
            acc[14] = fmaf(x3.z, w, acc[14]); acc[15] = fmaf(x3.w, w, acc[15]);
        }
        if (t < 117) {
#pragma unroll
            for (int r = 0; r < ROWS; ++r)
                t1l[(size_t)(base + r) * 128 + t] = (f16)acc[r];
        } else {
            int col = t - 117;
            float bb = b1[col];
#pragma unroll
            for (int r = 0; r < ROWS; ++r)
                t1r[(size_t)(base + r) * 120 + col] = acc[r] + bb;
        }
    } else if (t < 245) {          // zero-fill t1l pad cols 117..127
        int c = 117 + (t - 234);
#pragma unroll
        for (int r = 0; r < ROWS; ++r) t1l[(size_t)(base + r) * 128 + c] = (f16)0.f;
    } else if (t < 248) {          // zero-fill t1r pad cols 117..119
        int c = 117 + (t - 245);
#pragma unroll
        for (int r = 0; r < ROWS; ++r) t1r[(size_t)(base + r) * 120 + c] = 0.f;
    }
}

// ---- fused1: 2 nodes/wave. h1 = relu(gather(t1l)/deg + t1r); then
// ----         t2l = h1@Wl2 (f16), s2 = h1@Wr2 + b2.  grid = 25000, block = 64
__global__ __launch_bounds__(64) void k_fused1(
        const f16* __restrict__ t1l, const float* __restrict__ t1r,
        const int* __restrict__ cnt, const u16* __restrict__ bucket,
        const float* __restrict__ Wl2, const float* __restrict__ Wr2,
        const float* __restrict__ b2,
        f16* __restrict__ t2l, float* __restrict__ s2) {
    __shared__ __align__(16) float h1[2][120];
    int lane = threadIdx.x;
    int iA = blockIdx.x * 2, iB = iA + 1;
    int cA = cnt[iA], cB = cnt[iB];
    int nA = cA > CAP ? CAP : cA, nB = cB > CAP ? CAP : cB;
    int idsA = (int)bucket[(size_t)iA * CAP + lane];
    int idsB = (int)bucket[(size_t)iB * CAP + lane];
    int g = (lane < 30) ? 0 : 1;
    int d = lane - 30 * g;                 // qword index; valid < 30
    bool act = (lane < 60);
    int n_my = act ? (g ? nB : nA) : 0;
    int i_my = g ? iB : iA;
    float deg = fmaxf((float)(g ? cB : cA), 1.f);
    int dd = d < 31 ? d : 31;              // keep inactive-lane loads in-row
    int nmax = nA > nB ? nA : nB;
    float ax = 0.f, ay = 0.f, az = 0.f, aw = 0.f;
    const f16x4* src = (const f16x4*)t1l;  // 32 qwords per row
    for (int e0 = 0; e0 < nmax; e0 += 16) {
        f16x4 v[16];
#pragma unroll
        for (int u = 0; u < 16; ++u) {
            int e = e0 + u;
            int ra = __builtin_amdgcn_readlane(idsA, e & 63);
            int rb = __builtin_amdgcn_readlane(idsB, e & 63);
            int id = g ? rb : ra;
            id = (e < n_my) ? id : 0;
            v[u] = src[(size_t)id * 32 + dd];
        }
#pragma unroll
        for (int u = 0; u < 16; ++u) {
            int e = e0 + u;
            if (e < n_my) {
                ax += (float)v[u].x; ay += (float)v[u].y;
                az += (float)v[u].z; aw += (float)v[u].w;
            }
        }
    }
    if (act) {
        float4 s = ((const float4*)(t1r + (size_t)i_my * 120))[d];
        float4 hv;
        hv.x = fmaxf(ax / deg + s.x, 0.f);
        hv.y = fmaxf(ay / deg + s.y, 0.f);
        hv.z = fmaxf(az / deg + s.z, 0.f);
        hv.w = fmaxf(aw / deg + s.w, 0.f);
        *((float4*)&h1[g][4 * d]) = hv;
    }
    __syncthreads();
    int j = lane;
    if (j < 42) {
        float pA = 0.f, pB = 0.f, qA = 0.f, qB = 0.f;
        const float4* hA = (const float4*)&h1[0][0];
        const float4* hB = (const float4*)&h1[1][0];
#pragma unroll 4
        for (int kk = 0; kk < 29; ++kk) {       // k = 0..115
            float4 a = hA[kk], b = hB[kk];
            float av[4] = {a.x, a.y, a.z, a.w};
            float bv[4] = {b.x, b.y, b.z, b.w};
#pragma unroll
            for (int u = 0; u < 4; ++u) {
                int k = 4 * kk + u;
                float wl = Wl2[k * 42 + j], wr = Wr2[k * 42 + j];
                pA = fmaf(av[u], wl, pA); pB = fmaf(bv[u], wl, pB);
                qA = fmaf(av[u], wr, qA); qB = fmaf(bv[u], wr, qB);
            }
        }
        {   int k = 116;
            float wl = Wl2[k * 42 + j], wr = Wr2[k * 42 + j];
            float va = h1[0][k], vb = h1[1][k];
            pA = fmaf(va, wl, pA); pB = fmaf(vb, wl, pB);
            qA = fmaf(va, wr, qA); qB = fmaf(vb, wr, qB);
        }
        float bb = b2[j];
        t2l[(size_t)iA * 64 + j] = (f16)pA;
        t2l[(size_t)iB * 64 + j] = (f16)pB;
        s2[(size_t)iA * 42 + j] = qA + bb;
        s2[(size_t)iB * 42 + j] = qB + bb;
    }
}

// ---- fused2: 3 nodes/wave. h2 = relu(gather(t2l)/deg + s2); then
// ----         p = h2@[Wlm|Wlv] (f16), d_out self = h2@[Wrm|Wrv] + b.
// ----         grid = 16667, block = 64
__global__ __launch_bounds__(64) void k_fused2(
        const f16* __restrict__ t2l, const float* __restrict__ s2,
        const int* __restrict__ cnt, const u16* __restrict__ bucket,
        const float* __restrict__ Wlm, const float* __restrict__ Wrm,
        const float* __restrict__ bm,
        const float* __restrict__ Wlv, const float* __restrict__ Wrv,
        const float* __restrict__ bv,
        f16* __restrict__ p, float* __restrict__ out) {
    __shared__ __align__(16) float h2[3][48];
    int lane = threadIdx.x;
    int i0 = blockIdx.x * 3;
    int iA = i0, iB = i0 + 1, iC = i0 + 2;
    bool vA = iA < N_NODES, vB = iB < N_NODES, vC = iC < N_NODES;
    int cA = vA ? cnt[iA] : 0, cB = vB ? cnt[iB] : 0, cC = vC ? cnt[iC] : 0;
    int nA = cA > CAP ? CAP : cA, nB = cB > CAP ? CAP : cB, nC = cC > CAP ? CAP : cC;
    int idsA = vA ? (int)bucket[(size_t)iA * CAP + lane] : 0;
    int idsB = vB ? (int)bucket[(size_t)iB * CAP + lane] : 0;
    int idsC = vC ? (int)bucket[(size_t)iC * CAP + lane] : 0;
    int g = (lane < 21) ? 0 : (lane < 42 ? 1 : 2);
    int d = lane - 21 * g;                 // dword index; valid < 21 (lane 63 -> d 21)
    bool act = (lane < 63);
    int i_my = i0 + g;
    bool valid = act && (i_my < N_NODES);
    int n_my = valid ? (g == 0 ? nA : (g == 1 ? nB : nC)) : 0;
    float deg = fmaxf((float)(g == 0 ? cA : (g == 1 ? cB : cC)), 1.f);
    int nmax = nA > nB ? nA : nB; if (nC > nmax) nmax = nC;
    float ax = 0.f, ay = 0.f;
    const f16x2* src = (const f16x2*)t2l;  // 32 dwords per row
    for (int e0 = 0; e0 < nmax; e0 += 16) {
        f16x2 v[16];
#pragma unroll
        for (int u = 0; u < 16; ++u) {
            int e = e0 + u;
            int ra = __builtin_amdgcn_readlane(idsA, e & 63);
            int rb = __builtin_amdgcn_readlane(idsB, e & 63);
            int rc = __builtin_amdgcn_readlane(idsC, e & 63);
            int id = (g == 0) ? ra : ((g == 1) ? rb : rc);
            id = (e < n_my) ? id : 0;
            v[u] = src[(size_t)id * 32 + d];
        }
#pragma unroll
        for (int u = 0; u < 16; ++u) {
            int e = e0 + u;
            if (e < n_my) { ax += (float)v[u].x; ay += (float)v[u].y; }
        }
    }
    if (valid && d < 21) {
        float2 s = ((const float2*)(s2 + (size_t)i_my * 42))[d];
        h2[g][2 * d]     = fmaxf(ax / deg + s.x, 0.f);
        h2[g][2 * d + 1] = fmaxf(ay / deg + s.y, 0.f);
    }
    __syncthreads();
    int j = lane;
    if (j < 48) {
        int o = (j < 24) ? j : j - 24;
        const float* WL = (j < 24) ? Wlm : Wlv;
        const float* WR = (j < 24) ? Wrm : Wrv;
        float bias = (j < 24) ? bm[o] : bv[o];
        float pA = 0.f, pB = 0.f, pC = 0.f, qA = 0.f, qB = 0.f, qC = 0.f;
        const float4* hA = (const float4*)&h2[0][0];
        const float4* hB = (const float4*)&h2[1][0];
        const float4* hC = (const float4*)&h2[2][0];
#pragma unroll 2
        for (int kk = 0; kk < 10; ++kk) {       // k = 0..39
            float4 a = hA[kk], b = hB[kk], c = hC[kk];
            float av[4] = {a.x, a.y, a.z, a.w};
            float bv4[4] = {b.x, b.y, b.z, b.w};
            float cv[4] = {c.x, c.y, c.z, c.w};
#pragma unroll
            for (int u = 0; u < 4; ++u) {
                int k = 4 * kk + u;
                float wl = WL[k * 24 + o], wr = WR[k * 24 + o];
                pA = fmaf(av[u], wl, pA);  qA = fmaf(av[u], wr, qA);
                pB = fmaf(bv4[u], wl, pB); qB = fmaf(bv4[u], wr, qB);
                pC = fmaf(cv[u], wl, pC);  qC = fmaf(cv[u], wr, qC);
            }
        }
        for (int k = 40; k < 42; ++k) {
            float wl = WL[k * 24 + o], wr = WR[k * 24 + o];
            pA = fmaf(h2[0][k], wl, pA); qA = fmaf(h2[0][k], wr, qA);
            pB = fmaf(h2[1][k], wl, pB); qB = fmaf(h2[1][k], wr, qB);
            pC = fmaf(h2[2][k], wl, pC); qC = fmaf(h2[2][k], wr, qC);
        }
        size_t half = (j < 24) ? 0 : (size_t)N_NODES * 24;
        if (vA) { p[(size_t)iA * 64 + j] = (f16)pA; out[half + (size_t)iA * 24 + o] = qA + bias; }
        if (vB) { p[(size_t)iB * 64 + j] = (f16)pB; out[half + (size_t)iB * 24 + o] = qB + bias; }
        if (vC) { p[(size_t)iC * 64 + j] = (f16)pC; out[half + (size_t)iC * 24 + o] = qC + bias; }
    }
}

// ---- final: 2 nodes/wave, pure gather of p + RMW of self-term in d_out.
// ----        grid = 25000, block = 64
__global__ __launch_bounds__(64) void k_final(
        const f16* __restrict__ p, const int* __restrict__ cnt,
        const u16* __restrict__ bucket, float* __restrict__ out) {
    int lane = threadIdx.x;
    int iA = blockIdx.x * 2, iB = iA + 1;
    int cA = cnt[iA], cB = cnt[iB];
    int nA = cA > CAP ? CAP : cA, nB = cB > CAP ? CAP : cB;
    int idsA = (int)bucket[(size_t)iA * CAP + lane];
    int idsB = (int)bucket[(size_t)iB * CAP + lane];
    int g = (lane < 24) ? 0 : 1;
    int d = lane - 24 * g;                 // dword index; valid < 24
    bool act = (lane < 48);
    int n_my = act ? (g ? nB : nA) : 0;
    int i_my = g ? iB : iA;
    float deg = fmaxf((float)(g ? cB : cA), 1.f);
    int dd = d < 31 ? d : 31;
    int nmax = nA > nB ? nA : nB;
    float ax = 0.f, ay = 0.f;
    const f16x2* src = (const f16x2*)p;    // 32 dwords per row
    for (int e0 = 0; e0 < nmax; e0 += 16) {
        f16x2 v[16];
#pragma unroll
        for (int u = 0; u < 16; ++u) {
            int e = e0 + u;
            int ra = __builtin_amdgcn_readlane(idsA, e & 63);
            int rb = __builtin_amdgcn_readlane(idsB, e & 63);
            int id = g ? rb : ra;
            id = (e < n_my) ? id : 0;
            v[u] = src[(size_t)id * 32 + dd];
        }
#pragma unroll
        for (int u = 0; u < 16; ++u) {
            int e = e0 + u;
            if (e < n_my) { ax += (float)v[u].x; ay += (float)v[u].y; }
        }
    }
    if (act) {
        float mx = ax / deg, my = ay / deg;
        size_t addr = (d < 12) ? ((size_t)i_my * 24 + 2 * d)
                               : ((size_t)N_NODES * 24 + (size_t)i_my * 24 + 2 * (d - 12));
        float2 s = *(const float2*)(out + addr);
        float2 r; r.x = s.x + mx; r.y = s.y + my;
        *(float2*)(out + addr) = r;
    }
}

extern "C" void kernel_launch(void* const* d_in, const int* in_sizes, int n_in,
                              void* d_out, int out_size, void* d_ws, size_t ws_size,
                              hipStream_t stream) {
    const float* x   = (const float*)d_in[0];
    const int*   ei  = (const int*)d_in[1];
    const float* Wl1 = (const float*)d_in[2];
    const float* Wr1 = (const float*)d_in[3];
    const float* b1  = (const float*)d_in[4];
    const float* Wl2 = (const float*)d_in[5];
    const float* Wr2 = (const float*)d_in[6];
    const float* b2  = (const float*)d_in[7];
    const float* Wlm = (const float*)d_in[8];
    const float* Wrm = (const float*)d_in[9];
    const float* bm  = (const float*)d_in[10];
    const float* Wlv = (const float*)d_in[11];
    const float* Wrv = (const float*)d_in[12];
    const float* bv  = (const float*)d_in[13];
    float* out = (float*)d_out;

    // workspace layout (bytes):
    //   cnt    @ 0          : 200,000   (pad 204,800)
    //   bucket @ 204,800    : 50000*64*2  =  6,400,000 ->  6,604,800
    //   t1l    @ 6,604,800  : 50000*128*2 = 12,800,000 -> 19,404,800
    //   t1r    @ 19,404,800 : 50000*120*4 = 24,000,000 -> 43,404,800
    //   t2l    @ 43,404,800 : 50000*64*2  =  6,400,000 -> 49,804,800
    //   s2     @ 49,804,800 : 50000*42*4  =  8,400,000 -> 58,204,800
    //   p      @ 58,204,800 : 50000*64*2  =  6,400,000 -> 64,604,800
    char* ws = (char*)d_ws;
    int*   cnt    = (int*)(ws);
    u16*   bucket = (u16*)(ws + 204800);
    f16*   t1l    = (f16*)(ws + 6604800);
    float* t1r    = (float*)(ws + 19404800);
    f16*   t2l    = (f16*)(ws + 43404800);
    float* s2     = (float*)(ws + 49804800);
    f16*   p      = (f16*)(ws + 58204800);

    hipMemsetAsync(cnt, 0, N_NODES * sizeof(int), stream);
    k_build<<<(N_EDGES + 255) / 256, 256, 0, stream>>>(ei, cnt, bucket);
    k_gemm1<<<N_NODES / ROWS, 256, 0, stream>>>(x, Wl1, Wr1, b1, t1l, t1r);
    k_fused1<<<N_NODES / 2, 64, 0, stream>>>(t1l, t1r, cnt, bucket, Wl2, Wr2, b2, t2l, s2);
    k_fused2<<<(N_NODES + 2) / 3, 64, 0, stream>>>(t2l, s2, cnt, bucket,
                                                   Wlm, Wrm, bm, Wlv, Wrv, bv, p, out);
    k_final<<<N_NODES / 2, 64, 0, stream>>>(p, cnt, bucket, out);
}